// Round 5
// baseline (22.078 us; speedup 1.0000x reference)
//
#include <hip/hip_runtime.h>

#define N 2048
#define BATCH 32
#define BLOCK 256
#define SUBS 32                    // threads cooperating per query-quad
#define RQ 4                       // queries (i's) per thread
#define I_PER_BLOCK ((BLOCK / SUBS) * RQ)   // 32
#define SLICES (N / I_PER_BLOCK)            // 64 blocks per batch row
#define J4_PER_THREAD (N / 4 / SUBS)        // 16 float4 per thread

typedef float v2f __attribute__((ext_vector_type(2)));

// Each block: one (batch, 32-i slice). Row staged in LDS; each thread carries
// RQ=4 query accumulators so one ds_read_b128 feeds 16 (i,j) pairs — LDS
// traffic /4 vs R4 (was the binding pipe at 537 MB / 69 TB/s). exp args
// bounded (|x|max^2/16*log2e < 2), scale cancels in num/den.
__global__ __launch_bounds__(BLOCK, 8) void rank1_attn_kernel(
    const float* __restrict__ x, float* __restrict__ y) {
    __shared__ float sx[N];

    const int b     = blockIdx.x / SLICES;
    const int slice = blockIdx.x % SLICES;
    const int tid   = threadIdx.x;

    const float* xb = x + b * N;

    // ---- stage row into LDS (coalesced float4) ----
    const float4* xb4 = reinterpret_cast<const float4*>(xb);
    float4* sx4 = reinterpret_cast<float4*>(sx);
#pragma unroll
    for (int k = 0; k < 2; ++k) sx4[tid + k * BLOCK] = xb4[tid + k * BLOCK];
    __syncthreads();

    const int group = tid / SUBS;       // 0..7
    const int sub   = tid % SUBS;       // 0..31
    const int i0    = slice * I_PER_BLOCK + group * RQ;

    const float C = 1.4426950408889634f / 16.0f;   // log2(e)/16
    v2f tl2[RQ];
#pragma unroll
    for (int r = 0; r < RQ; ++r) {
        const float tl = sx[i0 + r] * C;
        tl2[r].x = tl; tl2[r].y = tl;
    }

    v2f den2[RQ], num2[RQ];
#pragma unroll
    for (int r = 0; r < RQ; ++r) { den2[r] = (v2f){0.f, 0.f}; num2[r] = (v2f){0.f, 0.f}; }

    const float4* s4 = reinterpret_cast<const float4*>(sx);
#pragma unroll 4
    for (int jj = 0; jj < J4_PER_THREAD; ++jj) {
        float4 v = s4[jj * SUBS + sub];
        v2f v01 = {v.x, v.y};
        v2f v23 = {v.z, v.w};
#pragma unroll
        for (int r = 0; r < RQ; ++r) {
            v2f a01 = tl2[r] * v01;            // v_pk_mul_f32
            v2f a23 = tl2[r] * v23;
            v2f e01, e23;
            e01.x = __builtin_amdgcn_exp2f(a01.x);
            e01.y = __builtin_amdgcn_exp2f(a01.y);
            e23.x = __builtin_amdgcn_exp2f(a23.x);
            e23.y = __builtin_amdgcn_exp2f(a23.y);
            den2[r] += e01;                    // v_pk_add_f32
            den2[r] += e23;
            num2[r] = e01 * v01 + num2[r];     // v_pk_fma_f32
            num2[r] = e23 * v23 + num2[r];
        }
    }

#pragma unroll
    for (int r = 0; r < RQ; ++r) {
        float den = den2[r].x + den2[r].y;
        float num = num2[r].x + num2[r].y;
        // reduce across the 32 cooperating lanes (within wave half)
#pragma unroll
        for (int off = 1; off < SUBS; off <<= 1) {
            den += __shfl_xor(den, off);
            num += __shfl_xor(num, off);
        }
        if (sub == 0) y[b * N + i0 + r] = num / den;
    }
}

extern "C" void kernel_launch(void* const* d_in, const int* in_sizes, int n_in,
                              void* d_out, int out_size, void* d_ws, size_t ws_size,
                              hipStream_t stream) {
    const float* x = (const float*)d_in[0];
    float* y = (float*)d_out;
    dim3 grid(BATCH * SLICES);
    dim3 block(BLOCK);
    rank1_attn_kernel<<<grid, block, 0, stream>>>(x, y);
}